// Round 3
// baseline (436.372 us; speedup 1.0000x reference)
//
#include <hip/hip_runtime.h>

// ---------------------------------------------------------------------------
// HolographicMemory fused v2: out = softmax(x @ [Kr|Ki]^T * temp) @ [Vr|Vi]
// 2 kernels: pack_kv (concat + temp fold, 1 MB each -> L2-resident),
//            fused (barrier-free K-loops, register-direct fragment loads).
// Per block: 64 x-rows, 512 threads (8 waves), wave w owns cols w*64..+64.
//   Phase 1: energy acc in regs; A-frags loaded fp32 from x + cvt->bf16,
//            B-frags loaded bf16 from Kb. NO LDS staging, NO barriers.
//   Softmax: exp in regs, row-sums via 16-lane shuffles + tiny LDS reduce;
//            unnormalized P -> LDS (bf16) for the A-layout transform.
//   Phase 2: A-frags ds_read from Ps, B-frags global from VbT, no barriers;
//            normalize by 1/rowsum in fp32 epilogue.
// ---------------------------------------------------------------------------

#define DIMX    1024
#define MEMN    512
#define NROWS   32768
#define TEMP    0.04419417382415922f  // 512^-0.5
#define PSTRIDE 520                   // 512+8: 16B-aligned rows, 2-way-free banks

typedef __bf16 bf16;
typedef __bf16 bf16x8 __attribute__((ext_vector_type(8)));
typedef float  f32x4  __attribute__((ext_vector_type(4)));

// --- pack K'*temp = [Kr|Ki] as [512][1024]; V'^T as [1024][512] (bf16) -----
__global__ __launch_bounds__(256) void pack_kv_kernel(const float* __restrict__ kr,
                                                      const float* __restrict__ ki,
                                                      const float* __restrict__ vr,
                                                      const float* __restrict__ vi,
                                                      bf16* __restrict__ Kb,
                                                      bf16* __restrict__ VbT) {
    const int idx = blockIdx.x * 256 + threadIdx.x;   // 0 .. 512*1024-1
    {   // Kb[m][h'] = temp * (h'<512 ? Kr[m][h'] : Ki[m][h'-512])
        const int m = idx >> 10, h = idx & 1023;
        const float v = (h < 512) ? kr[m * 512 + h] : ki[m * 512 + (h - 512)];
        Kb[idx] = (bf16)(v * TEMP);
    }
    {   // VbT[h'][m] : h'<512 -> Vr[m][h'], else Vi[m][h'-512]
        const int hp = idx >> 9, m = idx & 511;
        const float v = (hp < 512) ? vr[m * 512 + hp] : vi[m * 512 + (hp - 512)];
        VbT[idx] = (bf16)v;
    }
}

// ------------------------------ fused kernel -------------------------------
__global__ __launch_bounds__(512, 2) void fused_kernel(const float* __restrict__ x,
                                                       const bf16* __restrict__ Kb,
                                                       const bf16* __restrict__ VbT,
                                                       float* __restrict__ out) {
    __shared__ bf16  Ps[64 * PSTRIDE];   // 66,560 B
    __shared__ float red[8 * 64];        //  2,048 B
    __shared__ float inv_row[64];        //    256 B  (~69 KB total)

    const int tid  = threadIdx.x;
    const int wave = tid >> 6, lane = tid & 63;
    const int lm   = lane & 15;          // m (A) / n (B) / col (C) in 16-tile
    const int q    = lane >> 4;          // quad id
    const int lkb  = q * 8;              // k base within 32-chunk
    const int rowB = blockIdx.x * 64;

    f32x4 acc[4][4] = {};

    // ---------------- phase 1: energy = x_tile @ K'^T (K=1024) ------------
    // A: x[rowB + i*16 + lm][k0+lkb .. +8] fp32 -> bf16  (16 lines/wave-load)
    // B: Kb[w*64 + j*16 + lm][k0+lkb .. +8] bf16         (16 lines/wave-load)
    {
        const float* xA = x  + (size_t)(rowB + lm) * DIMX + lkb;
        const bf16*  Bp = Kb + (size_t)(wave * 64 + lm) * DIMX + lkb;
        #pragma unroll 2
        for (int k0 = 0; k0 < DIMX; k0 += 32) {
            bf16x8 af[4], bfj[4];
            #pragma unroll
            for (int i = 0; i < 4; ++i) {
                const float* p = xA + (size_t)i * 16 * DIMX + k0;
                f32x4 a0 = *(const f32x4*)p;
                f32x4 a1 = *(const f32x4*)(p + 4);
                bf16x8 t;
                t[0] = (bf16)a0[0]; t[1] = (bf16)a0[1];
                t[2] = (bf16)a0[2]; t[3] = (bf16)a0[3];
                t[4] = (bf16)a1[0]; t[5] = (bf16)a1[1];
                t[6] = (bf16)a1[2]; t[7] = (bf16)a1[3];
                af[i] = t;
            }
            #pragma unroll
            for (int j = 0; j < 4; ++j)
                bfj[j] = *(const bf16x8*)(Bp + (size_t)j * 16 * DIMX + k0);
            #pragma unroll
            for (int i = 0; i < 4; ++i)
                #pragma unroll
                for (int j = 0; j < 4; ++j)
                    acc[i][j] = __builtin_amdgcn_mfma_f32_16x16x32_bf16(
                        af[i], bfj[j], acc[i][j], 0, 0, 0);
        }
    }

    // ------------- softmax: exp in regs, row-sum shuffle reduce ------------
    // C layout: row = i*16 + q*4 + r, col = wave*64 + j*16 + lm
    {
        float rp[4][4];
        #pragma unroll
        for (int i = 0; i < 4; ++i)
            #pragma unroll
            for (int r = 0; r < 4; ++r) rp[i][r] = 0.f;
        #pragma unroll
        for (int i = 0; i < 4; ++i)
            #pragma unroll
            for (int j = 0; j < 4; ++j)
                #pragma unroll
                for (int r = 0; r < 4; ++r) {
                    float e = __expf(acc[i][j][r]);   // |logit| < ~0.3, safe
                    acc[i][j][r] = e;
                    rp[i][r] += e;
                }
        // reduce across the 16 lanes (lm) of each quad
        #pragma unroll
        for (int i = 0; i < 4; ++i)
            #pragma unroll
            for (int r = 0; r < 4; ++r) {
                float v = rp[i][r];
                v += __shfl_xor(v, 1);
                v += __shfl_xor(v, 2);
                v += __shfl_xor(v, 4);
                v += __shfl_xor(v, 8);
                if (lm == 0) red[wave * 64 + i * 16 + q * 4 + r] = v;
            }
        // unnormalized exp -> Ps
        #pragma unroll
        for (int i = 0; i < 4; ++i)
            #pragma unroll
            for (int j = 0; j < 4; ++j)
                #pragma unroll
                for (int r = 0; r < 4; ++r)
                    Ps[(i * 16 + q * 4 + r) * PSTRIDE + wave * 64 + j * 16 + lm]
                        = (bf16)acc[i][j][r];
    }
    __syncthreads();
    if (tid < 64) {
        float s = 0.f;
        #pragma unroll
        for (int w = 0; w < 8; ++w) s += red[w * 64 + tid];
        inv_row[tid] = 1.0f / s;
    }
    __syncthreads();

    float myinv[4][4];
    #pragma unroll
    for (int i = 0; i < 4; ++i)
        #pragma unroll
        for (int r = 0; r < 4; ++r)
            myinv[i][r] = inv_row[i * 16 + q * 4 + r];

    // ---------------- phase 2: out = P @ V'^T (K=512), 2 col-chunks --------
    #pragma unroll 1
    for (int oc = 0; oc < 2; ++oc) {
        #pragma unroll
        for (int i = 0; i < 4; ++i)
            #pragma unroll
            for (int j = 0; j < 4; ++j)
                acc[i][j] = (f32x4){0.f, 0.f, 0.f, 0.f};

        const bf16* Vp = VbT + (size_t)(oc * 512 + wave * 64 + lm) * MEMN + lkb;
        #pragma unroll 2
        for (int k0 = 0; k0 < MEMN; k0 += 32) {
            bf16x8 af[4], bfj[4];
            #pragma unroll
            for (int i = 0; i < 4; ++i)
                af[i] = *(const bf16x8*)(Ps + (i * 16 + lm) * PSTRIDE + k0 + lkb);
            #pragma unroll
            for (int j = 0; j < 4; ++j)
                bfj[j] = *(const bf16x8*)(Vp + (size_t)j * 16 * MEMN + k0);
            #pragma unroll
            for (int i = 0; i < 4; ++i)
                #pragma unroll
                for (int j = 0; j < 4; ++j)
                    acc[i][j] = __builtin_amdgcn_mfma_f32_16x16x32_bf16(
                        af[i], bfj[j], acc[i][j], 0, 0, 0);
        }

        // epilogue: normalize + store fp32
        #pragma unroll
        for (int i = 0; i < 4; ++i)
            #pragma unroll
            for (int j = 0; j < 4; ++j)
                #pragma unroll
                for (int r = 0; r < 4; ++r)
                    out[(size_t)(rowB + i * 16 + q * 4 + r) * DIMX
                        + oc * 512 + wave * 64 + j * 16 + lm]
                        = acc[i][j][r] * myinv[i][r];
    }
}

// ---------------------------------------------------------------------------
extern "C" void kernel_launch(void* const* d_in, const int* in_sizes, int n_in,
                              void* d_out, int out_size, void* d_ws, size_t ws_size,
                              hipStream_t stream) {
    const float* x  = (const float*)d_in[0];
    const float* kr = (const float*)d_in[1];
    const float* ki = (const float*)d_in[2];
    const float* vr = (const float*)d_in[3];
    const float* vi = (const float*)d_in[4];
    float* out = (float*)d_out;

    char* ws = (char*)d_ws;
    bf16* Kb  = (bf16*)ws;                    // 512*1024*2 = 1 MiB
    bf16* VbT = (bf16*)(ws + (size_t)1048576);// 1024*512*2 = 1 MiB

    pack_kv_kernel<<<2048, 256, 0, stream>>>(kr, ki, vr, vi, Kb, VbT);
    fused_kernel<<<512, 512, 0, stream>>>(x, Kb, VbT, out);
}

// Round 4
// 361.551 us; speedup vs baseline: 1.2069x; 1.2069x over previous
//
#include <hip/hip_runtime.h>

// ---------------------------------------------------------------------------
// HolographicMemory v4: out = softmax(x @ [Kr|Ki]^T * temp) @ [Vr|Vi]
// 3 kernels:
//   pack_kv : K'*temp [512][1024] bf16, V'^T [1024][512] bf16 (L2-resident)
//   gemm1   : P = exp(x @ K'^T) bf16 [32768][512]; row-partial sums psum[n][4]
//             (m97 128x128 tile; A staged fp32->cvt->ds_write, B via DMA)
//   gemm2   : out = (P @ V'^T) * 1/sum(psum[n]) fp32   (m97 128x128 tile)
// ---------------------------------------------------------------------------

#define DIMX   1024
#define MEMN   512
#define NROWS  32768
#define TEMP   0.04419417382415922f  // 512^-0.5

typedef __bf16 bf16;
typedef __bf16 bf16x8 __attribute__((ext_vector_type(8)));
typedef float  f32x4  __attribute__((ext_vector_type(4)));

__device__ __forceinline__ void gload_lds16(const void* g, void* l) {
    __builtin_amdgcn_global_load_lds(
        (const __attribute__((address_space(1))) unsigned*)g,
        (__attribute__((address_space(3))) unsigned*)l,
        16, 0, 0);
}

// --- pack K'*temp = [Kr|Ki] as [512][1024]; V'^T as [1024][512] (bf16) -----
__global__ __launch_bounds__(256) void pack_kv_kernel(const float* __restrict__ kr,
                                                      const float* __restrict__ ki,
                                                      const float* __restrict__ vr,
                                                      const float* __restrict__ vi,
                                                      bf16* __restrict__ Kb,
                                                      bf16* __restrict__ VbT) {
    const int idx = blockIdx.x * 256 + threadIdx.x;   // 0 .. 512*1024-1
    {   // Kb[m][h'] = temp * (h'<512 ? Kr[m][h'] : Ki[m][h'-512])
        const int m = idx >> 10, h = idx & 1023;
        const float v = (h < 512) ? kr[m * 512 + h] : ki[m * 512 + (h - 512)];
        Kb[idx] = (bf16)(v * TEMP);
    }
    {   // VbT[h'][m] : h'<512 -> Vr[m][h'], else Vi[m][h'-512]
        const int hp = idx >> 9, m = idx & 511;
        const float v = (hp < 512) ? vr[m * 512 + hp] : vi[m * 512 + (hp - 512)];
        VbT[idx] = (bf16)v;
    }
}

// ---------------- gemm1: P = exp(x @ K'^T), psum row partials --------------
// 128x128 tile, BK=32, 256 thr (4 waves 2x2). A = x fp32 (cvt in staging),
// B = Kb bf16 (global_load_lds). grid = (4, 256).
__global__ __launch_bounds__(256) void gemm1_kernel(const float* __restrict__ x,
                                                    const bf16* __restrict__ Kb,
                                                    bf16* __restrict__ P,
                                                    float* __restrict__ psum) {
    __shared__ bf16  As[128 * 32];
    __shared__ bf16  Bs[128 * 32];
    __shared__ float red[256];

    const int tid  = threadIdx.x;
    const int wave = tid >> 6, lane = tid & 63;
    const int lm   = lane & 15, q = lane >> 4, lkb = q * 8;
    const int rowB = blockIdx.y * 128;
    const int colB = blockIdx.x * 128;
    const int wrow = (wave >> 1) * 64;
    const int wcol = (wave & 1) * 64;

    // A staging: thread t -> row t>>1, fp32 cols (t&1)*16 .. +16
    const float* xp = x + (size_t)(rowB + (tid >> 1)) * DIMX + (tid & 1) * 16;
    bf16* awr = As + (tid >> 1) * 32 + (tid & 1) * 16;
    // B staging (m97): thread t -> rows {t>>2, t>>2+64}, bf16 cols (t&3)*8
    const bf16* Bb = Kb + (size_t)(colB + (tid >> 2)) * DIMX + (tid & 3) * 8;

    f32x4 a0 = *(const f32x4*)(xp);
    f32x4 a1 = *(const f32x4*)(xp + 4);
    f32x4 a2 = *(const f32x4*)(xp + 8);
    f32x4 a3 = *(const f32x4*)(xp + 12);

    f32x4 acc[4][4] = {};

    for (int k0 = 0; k0 < DIMX; k0 += 32) {
        __syncthreads();   // prev iter's frag reads done
        gload_lds16(Bb + k0,              Bs + wave * 512);
        gload_lds16(Bb + 64 * DIMX + k0,  Bs + 2048 + wave * 512);
        {   // cvt current A regs -> LDS bf16
            bf16x8 w0, w1;
            w0[0] = (bf16)a0[0]; w0[1] = (bf16)a0[1]; w0[2] = (bf16)a0[2]; w0[3] = (bf16)a0[3];
            w0[4] = (bf16)a1[0]; w0[5] = (bf16)a1[1]; w0[6] = (bf16)a1[2]; w0[7] = (bf16)a1[3];
            w1[0] = (bf16)a2[0]; w1[1] = (bf16)a2[1]; w1[2] = (bf16)a2[2]; w1[3] = (bf16)a2[3];
            w1[4] = (bf16)a3[0]; w1[5] = (bf16)a3[1]; w1[6] = (bf16)a3[2]; w1[7] = (bf16)a3[3];
            *(bf16x8*)(awr)     = w0;
            *(bf16x8*)(awr + 8) = w1;
        }
        __syncthreads();   // staging visible (drains B-DMA + lds writes)

        // issue next iter's A loads early: overlap with MFMA phase
        if (k0 + 32 < DIMX) {
            a0 = *(const f32x4*)(xp + k0 + 32);
            a1 = *(const f32x4*)(xp + k0 + 36);
            a2 = *(const f32x4*)(xp + k0 + 40);
            a3 = *(const f32x4*)(xp + k0 + 44);
        }

        bf16x8 af[4], bfj[4];
        #pragma unroll
        for (int i = 0; i < 4; ++i)
            af[i] = *(const bf16x8*)(As + (wrow + i * 16 + lm) * 32 + lkb);
        #pragma unroll
        for (int j = 0; j < 4; ++j)
            bfj[j] = *(const bf16x8*)(Bs + (wcol + j * 16 + lm) * 32 + lkb);
        #pragma unroll
        for (int i = 0; i < 4; ++i)
            #pragma unroll
            for (int j = 0; j < 4; ++j)
                acc[i][j] = __builtin_amdgcn_mfma_f32_16x16x32_bf16(
                    af[i], bfj[j], acc[i][j], 0, 0, 0);
    }

    // ---- epilogue: exp, store unnormalized P (bf16), row partial sums -----
    float s[4][4];
    #pragma unroll
    for (int i = 0; i < 4; ++i)
        #pragma unroll
        for (int r = 0; r < 4; ++r) s[i][r] = 0.f;

    const int r0 = rowB + wrow + q * 4;
    const int c0 = colB + wcol + lm;
    #pragma unroll
    for (int i = 0; i < 4; ++i)
        #pragma unroll
        for (int j = 0; j < 4; ++j)
            #pragma unroll
            for (int r = 0; r < 4; ++r) {
                float e = __expf(acc[i][j][r]);   // |logit| < ~0.3: safe, no max-sub
                s[i][r] += e;
                P[(size_t)(r0 + i * 16 + r) * MEMN + c0 + j * 16] = (bf16)e;
            }

    // reduce over 16 lm lanes (stay within quad: xor 1,2,4,8)
    #pragma unroll
    for (int i = 0; i < 4; ++i)
        #pragma unroll
        for (int r = 0; r < 4; ++r) {
            float v = s[i][r];
            v += __shfl_xor(v, 1);
            v += __shfl_xor(v, 2);
            v += __shfl_xor(v, 4);
            v += __shfl_xor(v, 8);
            if (lm == 0) red[(wave & 1) * 128 + wrow + i * 16 + q * 4 + r] = v;
        }
    __syncthreads();
    if (tid < 128)   // combine the two col-half waves; psum[n][4], col-block slot
        psum[(size_t)(rowB + tid) * 4 + blockIdx.x] = red[tid] + red[128 + tid];
}

// ---------------- gemm2: out = (P @ V'^T) * inv_rowsum ---------------------
// m97 128x128, K=512, both operands bf16 via global_load_lds. grid = (8,256).
__global__ __launch_bounds__(256) void gemm2_kernel(const bf16* __restrict__ P,
                                                    const bf16* __restrict__ VbT,
                                                    const float* __restrict__ psum,
                                                    float* __restrict__ out) {
    __shared__ bf16 As[128 * 32];
    __shared__ bf16 Bs[128 * 32];

    const int tid  = threadIdx.x;
    const int wave = tid >> 6, lane = tid & 63;
    const int lm   = lane & 15, q = lane >> 4, lkb = q * 8;
    const int rowB = blockIdx.y * 128;
    const int colB = blockIdx.x * 128;
    const int wrow = (wave >> 1) * 64;
    const int wcol = (wave & 1) * 64;

    const bf16* Ab = P   + (size_t)(rowB + (tid >> 2)) * MEMN + (tid & 3) * 8;
    const bf16* Bb = VbT + (size_t)(colB + (tid >> 2)) * MEMN + (tid & 3) * 8;

    f32x4 acc[4][4] = {};

    for (int k0 = 0; k0 < MEMN; k0 += 32) {
        __syncthreads();
        gload_lds16(Ab + k0,             As + wave * 512);
        gload_lds16(Ab + 64 * MEMN + k0, As + 2048 + wave * 512);
        gload_lds16(Bb + k0,             Bs + wave * 512);
        gload_lds16(Bb + 64 * MEMN + k0, Bs + 2048 + wave * 512);
        __syncthreads();

        bf16x8 af[4], bfj[4];
        #pragma unroll
        for (int i = 0; i < 4; ++i)
            af[i] = *(const bf16x8*)(As + (wrow + i * 16 + lm) * 32 + lkb);
        #pragma unroll
        for (int j = 0; j < 4; ++j)
            bfj[j] = *(const bf16x8*)(Bs + (wcol + j * 16 + lm) * 32 + lkb);
        #pragma unroll
        for (int i = 0; i < 4; ++i)
            #pragma unroll
            for (int j = 0; j < 4; ++j)
                acc[i][j] = __builtin_amdgcn_mfma_f32_16x16x32_bf16(
                    af[i], bfj[j], acc[i][j], 0, 0, 0);
    }

    // epilogue: normalize by 1/sum(psum[n][0..3]) and store fp32
    const int r0 = rowB + wrow + q * 4;
    const int c0 = colB + wcol + lm;
    #pragma unroll
    for (int i = 0; i < 4; ++i) {
        #pragma unroll
        for (int r = 0; r < 4; ++r) {
            const int row = r0 + i * 16 + r;
            f32x4 p = *(const f32x4*)(psum + (size_t)row * 4);
            const float inv = 1.0f / (p[0] + p[1] + p[2] + p[3]);
            #pragma unroll
            for (int j = 0; j < 4; ++j)
                out[(size_t)row * DIMX + c0 + j * 16] = acc[i][j][r] * inv;
        }
    }
}

// ---------------------------------------------------------------------------
extern "C" void kernel_launch(void* const* d_in, const int* in_sizes, int n_in,
                              void* d_out, int out_size, void* d_ws, size_t ws_size,
                              hipStream_t stream) {
    const float* x  = (const float*)d_in[0];
    const float* kr = (const float*)d_in[1];
    const float* ki = (const float*)d_in[2];
    const float* vr = (const float*)d_in[3];
    const float* vi = (const float*)d_in[4];
    float* out = (float*)d_out;

    char* ws = (char*)d_ws;
    bf16*  Kb   = (bf16*)ws;                                  //  1 MiB
    bf16*  VbT  = (bf16*)(ws + (size_t)1048576);              //  1 MiB
    bf16*  P    = (bf16*)(ws + (size_t)2097152);              // 32 MiB
    float* psum = (float*)(ws + (size_t)2097152 + 33554432);  // 512 KiB

    pack_kv_kernel<<<2048, 256, 0, stream>>>(kr, ki, vr, vi, Kb, VbT);
    gemm1_kernel<<<dim3(4, 256), 256, 0, stream>>>(x, Kb, P, psum);
    gemm2_kernel<<<dim3(8, 256), 256, 0, stream>>>(P, VbT, psum, out);
}